// Round 2
// baseline (102.848 us; speedup 1.0000x reference)
//
#include <hip/hip_runtime.h>
#include <math.h>

#define D_   363
#define A_   180
#define B_   4
#define IMG_ 256

// ---------------------------------------------------------------------------
// Kernel 1: build the real-space ramp-filter kernel g[n] = ifft(filt)[n]
//   filt[k] = 2*min(k, D-k)/D  (== |fftfreq(D)|*2 for odd D=363)
//   g[n] = (1/D) * sum_k filt[k] * cos(2*pi*k*n/D)
// Integer (k*n) % D argument reduction => cosf stays ~1-ulp accurate.
// Also fills cos/sin tables for the 180 projection angles (double precision).
// ---------------------------------------------------------------------------
__global__ __launch_bounds__(512)
void fbp_prep(float* __restrict__ h,
              float* __restrict__ ctab,
              float* __restrict__ stab) {
    __shared__ float red[512];
    const int n = blockIdx.x;   // 0..362  (output index of g)
    const int k = threadIdx.x;  // 0..511  (frequency index; >=363 contributes 0)

    float term = 0.0f;
    if (k < D_) {
        int mk = (k < D_ - k) ? k : (D_ - k);
        float filt = (2.0f * (float)mk) / (float)D_;
        int p = (k * n) % D_;                         // exact in int32
        float ang = (float)(2.0 * M_PI) * ((float)p / (float)D_);  // < 2*pi
        term = filt * cosf(ang);
    }
    red[k] = term;
    __syncthreads();
    #pragma unroll
    for (int s = 256; s > 0; s >>= 1) {
        if (k < s) red[k] += red[k + s];
        __syncthreads();
    }
    if (k == 0) h[n] = red[0] / (float)D_;

    if (n == 0 && k < A_) {
        // angles = linspace(0, pi, 180) -> step pi/179
        double a = (double)k * (M_PI / 179.0);
        ctab[k] = (float)cos(a);
        stab[k] = (float)sin(a);
    }
}

// ---------------------------------------------------------------------------
// Kernel 2: per-row circular convolution  filtered[n] = sum_m s[m]*g[(n-m) mod D]
// One block per (batch, angle) row. LDS-staged row + doubled kernel table
// (removes the modulo from the inner loop). 363*363 FMAs per block.
//   srow[m] is wave-uniform (broadcast, conflict-free);
//   hb[-m] is stride-1 across lanes (conflict-free).
// ---------------------------------------------------------------------------
__global__ __launch_bounds__(512)
void fbp_filter(const float* __restrict__ sino,
                const float* __restrict__ h,
                float* __restrict__ filtered) {
    __shared__ float srow[D_];
    __shared__ float hext[2 * D_];   // hext[j] = h[j % D]
    const int r   = blockIdx.x;      // 0 .. B_*A_-1 (rows are contiguous)
    const int tid = threadIdx.x;

    for (int j = tid; j < D_; j += 512)     srow[j] = sino[r * D_ + j];
    for (int j = tid; j < 2 * D_; j += 512) hext[j] = h[(j >= D_) ? (j - D_) : j];
    __syncthreads();

    if (tid < D_) {
        float acc = 0.0f;
        const float* hb = &hext[tid + D_];   // hb[-m] = h[(tid - m) mod D]
        #pragma unroll 8
        for (int m = 0; m < D_; ++m)
            acc = fmaf(srow[m], hb[-m], acc);
        filtered[r * D_ + tid] = acc;
    }
}

// ---------------------------------------------------------------------------
// Kernel 3: backprojection. One block per (batch, image row); thread = column.
//   t  = x*cos(a) + y*sin(a);  px = (t+1)*0.5*(D-1)
//   linear interp with the reference's exact out-of-range masking.
// filtered (1 MB total) stays L2/L3-resident; cos/sin broadcast from LDS.
// 1024 blocks x 256 thr = 4 blocks/CU = 16 waves/CU.
// ---------------------------------------------------------------------------
__global__ __launch_bounds__(256)
void fbp_backproj(const float* __restrict__ filtered,
                  const float* __restrict__ ctab,
                  const float* __restrict__ stab,
                  float* __restrict__ out) {
    __shared__ float cl[A_], sl[A_];
    const int tid = threadIdx.x;          // column j
    if (tid < A_) { cl[tid] = ctab[tid]; sl[tid] = stab[tid]; }
    __syncthreads();

    const int i = blockIdx.x & (IMG_ - 1);  // image row
    const int b = blockIdx.x >> 8;          // batch
    const float y = -1.0f + 2.0f * (float)i   / 255.0f;  // coords[i]
    const float x = -1.0f + 2.0f * (float)tid / 255.0f;  // coords[j]

    const float* fb = filtered + b * (A_ * D_);
    float acc = 0.0f;

    for (int a = 0; a < A_; ++a) {
        float t  = x * cl[a] + y * sl[a];
        float px = (t + 1.0f) * 0.5f * 362.0f;   // 0.5*(D-1), ref associativity
        float fi = floorf(px);
        float frac = px - fi;
        int i0 = (int)fi;
        int i1 = i0 + 1;
        float w0 = (i0 >= 0 && i0 <= D_ - 1) ? (1.0f - frac) : 0.0f;
        float w1 = (i1 >= 0 && i1 <= D_ - 1) ? frac          : 0.0f;
        int i0c = min(max(i0, 0), D_ - 1);
        int i1c = min(max(i1, 0), D_ - 1);
        const float* row = fb + a * D_;
        acc = fmaf(row[i0c], w0, acc);
        acc = fmaf(row[i1c], w1, acc);
    }
    out[blockIdx.x * IMG_ + tid] = acc * (float)(M_PI / 180.0);
}

// ---------------------------------------------------------------------------
extern "C" void kernel_launch(void* const* d_in, const int* in_sizes, int n_in,
                              void* d_out, int out_size, void* d_ws, size_t ws_size,
                              hipStream_t stream) {
    const float* sino = (const float*)d_in[0];
    float* out = (float*)d_out;
    float* ws  = (float*)d_ws;

    // workspace layout (floats):
    //   [0,384)    : g (ramp kernel, 363 used)
    //   [384,576)  : cos table (180 used)
    //   [576,768)  : sin table (180 used)
    //   [768, ...) : filtered sinogram, B*A*D = 261360 floats (~1.05 MB)
    float* h        = ws;
    float* ctab     = ws + 384;
    float* stab     = ws + 576;
    float* filtered = ws + 768;

    fbp_prep    <<<D_,         512, 0, stream>>>(h, ctab, stab);
    fbp_filter  <<<B_ * A_,    512, 0, stream>>>(sino, h, filtered);
    fbp_backproj<<<B_ * IMG_, IMG_, 0, stream>>>(filtered, ctab, stab, out);
}

// Round 3
// 96.242 us; speedup vs baseline: 1.0686x; 1.0686x over previous
//
#include <hip/hip_runtime.h>
#include <math.h>

#define D_   363
#define A_   180
#define B_   4
#define IMG_ 256

// ---------------------------------------------------------------------------
// Kernel 1: build the real-space ramp-filter kernel g[n] = ifft(filt)[n]
//   filt[k] = 2*min(k, D-k)/D  (== |fftfreq(D)|*2 for odd D=363)
//   g[n] = (1/D) * sum_k filt[k] * cos(2*pi*k*n/D)
// Integer (k*n) % D argument reduction => cosf stays ~1-ulp accurate.
// Also fills cos/sin tables for the 180 projection angles (double precision).
// ---------------------------------------------------------------------------
__global__ __launch_bounds__(512)
void fbp_prep(float* __restrict__ h,
              float* __restrict__ ctab,
              float* __restrict__ stab) {
    __shared__ float red[512];
    const int n = blockIdx.x;   // 0..362  (output index of g)
    const int k = threadIdx.x;  // 0..511  (frequency index; >=363 contributes 0)

    float term = 0.0f;
    if (k < D_) {
        int mk = (k < D_ - k) ? k : (D_ - k);
        float filt = (2.0f * (float)mk) / (float)D_;
        int p = (k * n) % D_;                         // exact in int32
        float ang = (float)(2.0 * M_PI) * ((float)p / (float)D_);  // < 2*pi
        term = filt * cosf(ang);
    }
    red[k] = term;
    __syncthreads();
    #pragma unroll
    for (int s = 256; s > 0; s >>= 1) {
        if (k < s) red[k] += red[k + s];
        __syncthreads();
    }
    if (k == 0) h[n] = red[0] / (float)D_;

    if (n == 0 && k < A_) {
        // angles = linspace(0, pi, 180) -> step pi/179
        double a = (double)k * (M_PI / 179.0);
        ctab[k] = (float)cos(a);
        stab[k] = (float)sin(a);
    }
}

// ---------------------------------------------------------------------------
// Kernel 2: per-row circular convolution  filtered[n] = sum_m s[m]*h[(n-m) mod D]
// One block per (batch, angle) row, 384 threads (363 active in compute).
//  - s[m] is wave-uniform and loop-uniform -> read from global (s_load path,
//    scalar cache), keeping it OFF the LDS pipe.
//  - h taps come from an LDS float4 table hext4[j] = {h[j],h[j-1],h[j-2],h[j-3]}
//    (indices mod D). Lane n at m reads hext4[n + D - m]: consecutive lanes ->
//    consecutive 16B -> one conflict-free ds_read_b128 per 4 taps.
//      pairing: s[m]*hv.x + s[m+1]*hv.y + s[m+2]*hv.z + s[m+3]*hv.w
//               = s[m]h[n-m] + s[m+1]h[n-m-1] + s[m+2]h[n-m-2] + s[m+3]h[n-m-3]
// ---------------------------------------------------------------------------
__global__ __launch_bounds__(384)
void fbp_filter(const float* __restrict__ sino,
                const float* __restrict__ h,
                float* __restrict__ filtered) {
    __shared__ float4 hext4[2 * D_];   // j in [0, 726): 11.6 KB
    const int r   = blockIdx.x;        // 0 .. B_*A_-1 (rows contiguous)
    const int tid = threadIdx.x;

    for (int j = tid; j < 2 * D_; j += 384) {
        float a = h[ j              % D_];
        float b = h[(j - 1 + D_)    % D_];
        float c = h[(j - 2 + D_)    % D_];
        float d = h[(j - 3 + D_)    % D_];
        hext4[j] = make_float4(a, b, c, d);
    }
    __syncthreads();

    if (tid < D_) {
        const float* srow_g = sino + r * D_;   // uniform-index reads -> s_load
        float acc = 0.0f;
        int base = tid + D_;                   // j = tid + D - m
        #pragma unroll 5
        for (int m = 0; m < 360; m += 4) {
            float s0 = srow_g[m];
            float s1 = srow_g[m + 1];
            float s2 = srow_g[m + 2];
            float s3 = srow_g[m + 3];
            float4 hv = hext4[base - m];
            acc = fmaf(s0, hv.x, acc);
            acc = fmaf(s1, hv.y, acc);
            acc = fmaf(s2, hv.z, acc);
            acc = fmaf(s3, hv.w, acc);
        }
        // tail m = 360, 361, 362
        {
            float4 hv = hext4[base - 360];     // {h[n-360], h[n-361], h[n-362], .}
            acc = fmaf(srow_g[360], hv.x, acc);
            acc = fmaf(srow_g[361], hv.y, acc);
            acc = fmaf(srow_g[362], hv.z, acc);
        }
        filtered[r * D_ + tid] = acc;
    }
}

// ---------------------------------------------------------------------------
// Kernel 3: backprojection, 16x16 image tiles.
// block = 256 threads = one 16x16 tile of one batch image; lane row ty=tid>>4.
// Per-wave detector-index span ~ (16|cos|+4|sin|)*1.42 <= ~32 cells -> 2-3
// cache lines per gather (vs 6-7 with a full-row mapping). filtered (1 MB)
// is L2-resident; rows get L1 reuse across in-CU blocks at the same angle.
// ---------------------------------------------------------------------------
__global__ __launch_bounds__(256)
void fbp_backproj(const float* __restrict__ filtered,
                  const float* __restrict__ ctab,
                  const float* __restrict__ stab,
                  float* __restrict__ out) {
    __shared__ float cl[A_], sl[A_];
    const int tid = threadIdx.x;
    if (tid < A_) { cl[tid] = ctab[tid]; sl[tid] = stab[tid]; }
    __syncthreads();

    const int tile = blockIdx.x & 255;      // 16x16 tiles per image
    const int b    = blockIdx.x >> 8;       // batch
    const int ty   = tid >> 4, tx = tid & 15;
    const int i = ((tile >> 4) << 4) + ty;  // image row
    const int j = ((tile & 15) << 4) + tx;  // image col

    const float y = -1.0f + 2.0f * (float)i / 255.0f;  // coords[i]
    const float x = -1.0f + 2.0f * (float)j / 255.0f;  // coords[j]

    const float* fb = filtered + b * (A_ * D_);
    float acc = 0.0f;

    for (int a = 0; a < A_; ++a) {
        float t  = x * cl[a] + y * sl[a];
        float px = (t + 1.0f) * 0.5f * 362.0f;   // 0.5*(D-1), ref associativity
        float fi = floorf(px);
        float frac = px - fi;
        int i0 = (int)fi;
        int i1 = i0 + 1;
        float w0 = (i0 >= 0 && i0 <= D_ - 1) ? (1.0f - frac) : 0.0f;
        float w1 = (i1 >= 0 && i1 <= D_ - 1) ? frac          : 0.0f;
        int i0c = min(max(i0, 0), D_ - 1);
        int i1c = min(max(i1, 0), D_ - 1);
        const float* row = fb + a * D_;
        acc = fmaf(row[i0c], w0, acc);
        acc = fmaf(row[i1c], w1, acc);
    }
    out[(b << 16) + i * IMG_ + j] = acc * (float)(M_PI / 180.0);
}

// ---------------------------------------------------------------------------
extern "C" void kernel_launch(void* const* d_in, const int* in_sizes, int n_in,
                              void* d_out, int out_size, void* d_ws, size_t ws_size,
                              hipStream_t stream) {
    const float* sino = (const float*)d_in[0];
    float* out = (float*)d_out;
    float* ws  = (float*)d_ws;

    // workspace layout (floats):
    //   [0,384)    : h (ramp kernel, 363 used)
    //   [384,576)  : cos table (180 used)
    //   [576,768)  : sin table (180 used)
    //   [768, ...) : filtered sinogram, B*A*D = 261360 floats (~1.05 MB)
    float* h        = ws;
    float* ctab     = ws + 384;
    float* stab     = ws + 576;
    float* filtered = ws + 768;

    fbp_prep    <<<D_,       512, 0, stream>>>(h, ctab, stab);
    fbp_filter  <<<B_ * A_,  384, 0, stream>>>(sino, h, filtered);
    fbp_backproj<<<B_ * IMG_, 256, 0, stream>>>(filtered, ctab, stab, out);
}

// Round 11
// 92.165 us; speedup vs baseline: 1.1159x; 1.0442x over previous
//
#include <hip/hip_runtime.h>
#include <math.h>

#define D_   363
#define A_   180
#define B_   4
#define IMG_ 256

// ---------------------------------------------------------------------------
// Kernel 1: ramp filter as circular convolution, h computed in closed form.
//   filtered[n] = sum_m s[m] * h[(n-m) mod D]
//   h[n] = (4/D^2) * Sum_{k=1}^{181} k cos(2*pi*k*n/D)
//        = (4/D^2) * [182 cos(181*th) - 181 cos(182*th) - 1] / (4 sin^2(th/2)),
//     th = 2*pi*n/D  (exact integer mod-363 reduction keeps float trig tight;
//     h[0] = 2*181*182/D^2).
// One block per (batch,angle) row, 384 threads (363 compute lanes).
// Inner loop: per-lane ds_read_b128 of a pre-shifted float4 h-table +
// broadcast ds_read_b128 of the staged s-row (same-address = conflict-free).
// srow[363] = 0 pads the tail -> exactly 91 iterations, no remainder.
//
// Index algebra (the R4 bug, now fixed): hext4[j][c] = h[(j-c) mod D];
// we need h[(n - (4q+c)) mod D]  =>  j = n + D - 4q  (NOT n + D - q).
// ---------------------------------------------------------------------------
__global__ __launch_bounds__(384)
void fbp_filter(const float* __restrict__ sino,
                float* __restrict__ filtered) {
    __shared__ __align__(16) float  srow[364];
    __shared__ float                hval[D_];
    __shared__ __align__(16) float4 hext4[2 * D_];   // hext4[j] = {h[j],h[j-1],h[j-2],h[j-3]} (mod D)
    const int r   = blockIdx.x;      // 0 .. B_*A_-1 (rows contiguous)
    const int tid = threadIdx.x;

    if (tid < D_) {
        srow[tid] = sino[r * D_ + tid];         // coalesced, one shot
        float hn;
        if (tid == 0) {
            hn = 65884.0f / 131769.0f;          // 2*181*182 / 363^2
        } else {
            int p1 = (181 * tid) % D_;          // exact reduction of 181*th
            int p2 = (182 * tid) % D_;          // exact reduction of 182*th
            float c1 = cosf(6.28318530717958647692f * ((float)p1 * (1.0f / 363.0f)));
            float c2 = cosf(6.28318530717958647692f * ((float)p2 * (1.0f / 363.0f)));
            float sh = sinf(3.14159265358979323846f * ((float)tid * (1.0f / 363.0f)));
            float S  = (182.0f * c1 - 181.0f * c2 - 1.0f) / (4.0f * sh * sh);
            hn = S * (4.0f / 131769.0f);
        }
        hval[tid] = hn;
    }
    if (tid == D_) srow[D_] = 0.0f;             // zero pad (tid 363 exists)
    __syncthreads();

    for (int j = tid; j < 2 * D_; j += 384) {
        float a = hval[ j            % D_];
        float b = hval[(j + D_ - 1)  % D_];
        float c = hval[(j + D_ - 2)  % D_];
        float d = hval[(j + D_ - 3)  % D_];
        hext4[j] = make_float4(a, b, c, d);
    }
    __syncthreads();

    if (tid < D_) {
        float acc = 0.0f;
        #pragma unroll 7
        for (int q = 0; q < 91; ++q) {
            float4 sv = *(const float4*)&srow[4 * q];   // broadcast b128
            float4 hv = hext4[tid + D_ - 4 * q];        // per-lane b128 (FIXED: -4q)
            acc = fmaf(sv.x, hv.x, acc);
            acc = fmaf(sv.y, hv.y, acc);
            acc = fmaf(sv.z, hv.z, acc);
            acc = fmaf(sv.w, hv.w, acc);
        }
        filtered[r * D_ + tid] = acc;
    }
}

// ---------------------------------------------------------------------------
// Kernel 2: backprojection, 16x16 image tiles, angle tables built in-block.
//   px = x*(181*cos a) + y*(181*sin a) + 181   (folded affine map)
//   linear interp with the reference's exact out-of-range masking.
// #pragma unroll 4 -> 8 independent L2 gathers in flight per wave.
// ---------------------------------------------------------------------------
__global__ __launch_bounds__(256)
void fbp_backproj(const float* __restrict__ filtered,
                  float* __restrict__ out) {
    __shared__ float cl[A_], sl[A_];
    const int tid = threadIdx.x;
    if (tid < A_) {
        // angles = linspace(0, pi, 180): step pi/179 (double), then float trig
        float a = (float)((double)tid * (3.14159265358979323846 / 179.0));
        float sn, cn;
        sincosf(a, &sn, &cn);
        cl[tid] = 181.0f * cn;
        sl[tid] = 181.0f * sn;
    }
    __syncthreads();

    const int tile = blockIdx.x & 255;      // 16x16 tiles per image
    const int b    = blockIdx.x >> 8;       // batch
    const int ty   = tid >> 4, tx = tid & 15;
    const int i = ((tile >> 4) << 4) + ty;  // image row
    const int j = ((tile & 15) << 4) + tx;  // image col

    const float y = -1.0f + 2.0f * (float)i / 255.0f;  // coords[i]
    const float x = -1.0f + 2.0f * (float)j / 255.0f;  // coords[j]

    const float* __restrict__ fb = filtered + b * (A_ * D_);
    float acc = 0.0f;

    #pragma unroll 4
    for (int a = 0; a < A_; ++a) {
        float px = fmaf(x, cl[a], fmaf(y, sl[a], 181.0f));
        float fi = floorf(px);
        float frac = px - fi;
        int i0 = (int)fi;
        int i1 = i0 + 1;
        float w0 = ((unsigned)i0 <= (unsigned)(D_ - 1)) ? (1.0f - frac) : 0.0f;
        float w1 = ((unsigned)i1 <= (unsigned)(D_ - 1)) ? frac          : 0.0f;
        int i0c = min(max(i0, 0), D_ - 1);
        int i1c = min(max(i1, 0), D_ - 1);
        const float* row = fb + a * D_;
        acc = fmaf(row[i0c], w0, acc);
        acc = fmaf(row[i1c], w1, acc);
    }
    out[(b << 16) + i * IMG_ + j] = acc * (float)(M_PI / 180.0);
}

// ---------------------------------------------------------------------------
extern "C" void kernel_launch(void* const* d_in, const int* in_sizes, int n_in,
                              void* d_out, int out_size, void* d_ws, size_t ws_size,
                              hipStream_t stream) {
    const float* sino = (const float*)d_in[0];
    float* out = (float*)d_out;
    float* filtered = (float*)d_ws;   // B*A*D = 261360 floats (~1.05 MB)

    fbp_filter  <<<B_ * A_,   384, 0, stream>>>(sino, filtered);
    fbp_backproj<<<B_ * IMG_, 256, 0, stream>>>(filtered, out);
}

// Round 14
// 85.528 us; speedup vs baseline: 1.2025x; 1.0776x over previous
//
#include <hip/hip_runtime.h>
#include <math.h>

#define D_   363
#define A_   180
#define B_   4
#define IMG_ 256
#define W_   36    // per-angle LDS window width: max tile px-span 30.12 -> idx<=31, idx+1<=32

// ---------------------------------------------------------------------------
// Kernel 1: ramp filter as circular convolution, h computed in closed form.
//   filtered[n] = sum_m s[m] * h[(n-m) mod D]
//   h[n] = (4/D^2) * [182 cos(181*th) - 181 cos(182*th) - 1] / (4 sin^2(th/2)),
//     th = 2*pi*n/D;  h[0] = 2*181*182/D^2.  (verified vs FFT definition)
// One block per (batch,angle) row, 384 threads (363 compute lanes).
// Inner loop: per-lane ds_read_b128 of the pre-shifted float4 h-table +
// broadcast ds_read_b128 of the staged s-row. srow[363]=0 pads the tail.
// Index algebra: hext4[j][c] = h[(j-c) mod D]; need j = n + D - 4q.
// ---------------------------------------------------------------------------
__global__ __launch_bounds__(384)
void fbp_filter(const float* __restrict__ sino,
                float* __restrict__ filtered) {
    __shared__ __align__(16) float  srow[364];
    __shared__ float                hval[D_];
    __shared__ __align__(16) float4 hext4[2 * D_];
    const int r   = blockIdx.x;      // 0 .. B_*A_-1 (rows contiguous)
    const int tid = threadIdx.x;

    if (tid < D_) {
        srow[tid] = sino[r * D_ + tid];
        float hn;
        if (tid == 0) {
            hn = 65884.0f / 131769.0f;          // 2*181*182 / 363^2
        } else {
            int p1 = (181 * tid) % D_;
            int p2 = (182 * tid) % D_;
            float c1 = cosf(6.28318530717958647692f * ((float)p1 * (1.0f / 363.0f)));
            float c2 = cosf(6.28318530717958647692f * ((float)p2 * (1.0f / 363.0f)));
            float sh = sinf(3.14159265358979323846f * ((float)tid * (1.0f / 363.0f)));
            float S  = (182.0f * c1 - 181.0f * c2 - 1.0f) / (4.0f * sh * sh);
            hn = S * (4.0f / 131769.0f);
        }
        hval[tid] = hn;
    }
    if (tid == D_) srow[D_] = 0.0f;
    __syncthreads();

    for (int j = tid; j < 2 * D_; j += 384) {
        float a = hval[ j            % D_];
        float b = hval[(j + D_ - 1)  % D_];
        float c = hval[(j + D_ - 2)  % D_];
        float d = hval[(j + D_ - 3)  % D_];
        hext4[j] = make_float4(a, b, c, d);
    }
    __syncthreads();

    if (tid < D_) {
        float acc = 0.0f;
        #pragma unroll 7
        for (int q = 0; q < 91; ++q) {
            float4 sv = *(const float4*)&srow[4 * q];   // broadcast b128
            float4 hv = hext4[tid + D_ - 4 * q];        // per-lane b128
            acc = fmaf(sv.x, hv.x, acc);
            acc = fmaf(sv.y, hv.y, acc);
            acc = fmaf(sv.z, hv.z, acc);
            acc = fmaf(sv.w, hv.w, acc);
        }
        filtered[r * D_ + tid] = acc;
    }
}

// ---------------------------------------------------------------------------
// Kernel 2: backprojection, 16x16 tiles, gather-free inner loop.
// Per block: stage a 36-float detector window per angle in LDS (25.9 KB),
// loaded coalesced; the 180-angle loop is then pure VALU + 2 LDS reads.
//   base_a = floor(min px over 4 tile corners)  (fma monotone => bounds all
//   lanes' px; 4-corner min also covers sinf(pi_float)<0);
//   idx = i0 - base in [0,31], idx+1 <= 32 < 36.
// Windows load row[clamp(base+w)] so masked lanes read finite values x 0.
// Values and summation order are bit-identical to the R11 kernel.
// ---------------------------------------------------------------------------
__global__ __launch_bounds__(256)
void fbp_backproj(const float* __restrict__ filtered,
                  float* __restrict__ out) {
    __shared__ float4 csb[A_];          // {181*cos, 181*sin, (float)base, 0}
    __shared__ float  win[A_ * W_];     // 180 x 36 windows
    const int tid  = threadIdx.x;
    const int tile = blockIdx.x & 255;
    const int b    = blockIdx.x >> 8;
    const int ty   = tid >> 4, tx = tid & 15;
    const int r0   = ((tile >> 4) << 4);    // tile row start
    const int c0   = ((tile & 15) << 4);    // tile col start
    const int i = r0 + ty;                  // image row
    const int j = c0 + tx;                  // image col

    if (tid < A_) {
        float a = (float)((double)tid * (3.14159265358979323846 / 179.0));
        float sn, cn;
        sincosf(a, &sn, &cn);
        float C = 181.0f * cn, S = 181.0f * sn;
        float xa = -1.0f + 2.0f * (float)c0        / 255.0f;
        float xb = -1.0f + 2.0f * (float)(c0 + 15) / 255.0f;
        float ya = -1.0f + 2.0f * (float)r0        / 255.0f;
        float yb = -1.0f + 2.0f * (float)(r0 + 15) / 255.0f;
        float p00 = fmaf(xa, C, fmaf(ya, S, 181.0f));
        float p01 = fmaf(xb, C, fmaf(ya, S, 181.0f));
        float p10 = fmaf(xa, C, fmaf(yb, S, 181.0f));
        float p11 = fmaf(xb, C, fmaf(yb, S, 181.0f));
        float pmin = fminf(fminf(p00, p01), fminf(p10, p11));
        csb[tid] = make_float4(C, S, floorf(pmin), 0.0f);
    }
    __syncthreads();

    const float* __restrict__ fb = filtered + b * (A_ * D_);
    for (int u = tid; u < A_ * W_; u += 256) {
        int a   = u / W_;                    // magic-mul
        int w   = u - a * W_;
        int idx = (int)csb[a].z + w;
        idx = min(max(idx, 0), D_ - 1);      // clamped load; masked lanes x 0
        win[u] = fb[a * D_ + idx];
    }
    __syncthreads();

    const float y = -1.0f + 2.0f * (float)i / 255.0f;
    const float x = -1.0f + 2.0f * (float)j / 255.0f;
    float acc = 0.0f;

    #pragma unroll 4
    for (int a = 0; a < A_; ++a) {
        float4 cb = csb[a];                          // broadcast b128
        float px = fmaf(x, cb.x, fmaf(y, cb.y, 181.0f));
        float fi = floorf(px);
        float frac = px - fi;
        int i0 = (int)fi;
        int idx = i0 - (int)cb.z;                    // in [0, 31]
        float w0 = ((unsigned)i0       <= (unsigned)(D_ - 1)) ? (1.0f - frac) : 0.0f;
        float w1 = ((unsigned)(i0 + 1) <= (unsigned)(D_ - 1)) ? frac          : 0.0f;
        const float* wrow = &win[a * W_];
        acc = fmaf(wrow[idx],     w0, acc);
        acc = fmaf(wrow[idx + 1], w1, acc);
    }
    out[(b << 16) + i * IMG_ + j] = acc * (float)(M_PI / 180.0);
}

// ---------------------------------------------------------------------------
extern "C" void kernel_launch(void* const* d_in, const int* in_sizes, int n_in,
                              void* d_out, int out_size, void* d_ws, size_t ws_size,
                              hipStream_t stream) {
    const float* sino = (const float*)d_in[0];
    float* out = (float*)d_out;
    float* filtered = (float*)d_ws;   // B*A*D = 261360 floats (~1.05 MB)

    fbp_filter  <<<B_ * A_,   384, 0, stream>>>(sino, filtered);
    fbp_backproj<<<B_ * IMG_, 256, 0, stream>>>(filtered, out);
}